// Round 6
// baseline (450.250 us; speedup 1.0000x reference)
//
#include <hip/hip_runtime.h>
#include <hip/hip_cooperative_groups.h>
#include <math.h>

namespace cg = cooperative_groups;

#define B   8
#define NA  33600
#define M   64
#define NC  80
#define KK  13
#define EPSF 1e-9f
#define PIF 3.14159265358979323846f

#define PCAP 1536          // per-(b,m) positive capacity (max in-circle ~1100)
#define NBLK 1024          // co-resident: 4 blocks/CU x 256 CU
#define TPB  256

// ---------------------------------------------------------------- helpers

__device__ __forceinline__ float circle_iou(float gx, float gy, float gr,
                                            float px, float py, float pr) {
    float dx = gx - px, dy = gy - py;
    float d  = sqrtf(dx * dx + dy * dy + 1e-12f);
    float r0sq = gr * gr, r1sq = pr * pr;
    float d1 = (r0sq - r1sq + d * d) / (2.0f * d);
    float d2 = d - d1;
    float t0 = fminf(fmaxf(d1 / fmaxf(gr, EPSF), -1.0f), 1.0f);
    float t1 = fminf(fmaxf(d2 / fmaxf(pr, EPSF), -1.0f), 1.0f);
    float a0 = r0sq * acosf(t0) - d1 * sqrtf(fmaxf(r0sq - d1 * d1, 0.0f));
    float a1 = r1sq * acosf(t1) - d2 * sqrtf(fmaxf(r1sq - d2 * d2, 0.0f));
    float lens = a0 + a1;
    float rmin = fminf(gr, pr);
    float contained = PIF * rmin * rmin;
    float inter = (d >= gr + pr) ? 0.0f
                : ((d <= fabsf(gr - pr)) ? contained : lens);
    float uni = PIF * r0sq + PIF * r1sq - inter;
    return (uni > 0.0f) ? inter / uni : 0.0f;
}

// masked overlap + align_metric for one (b, gt, anchor) — reference formula
__device__ __forceinline__ void ov_met(const float* __restrict__ pd_scores,
                                       const float* __restrict__ pd_circles,
                                       const float* __restrict__ anc,
                                       int b, int a,
                                       float gx, float gy, float gr, int gl, float gmask,
                                       float* ov_out, float* met_out) {
    float ax = anc[2 * a], ay = anc[2 * a + 1];
    float dx = ax - gx, dy = ay - gy;
    float dan = sqrtf(dx * dx + dy * dy);
    float ov = 0.0f, met = 0.0f;
    if (gmask > 0.0f && dan < gr) {
        int base = (b * NA + a) * 3;
        float px = pd_circles[base + 0];
        float py = pd_circles[base + 1];
        float pr = pd_circles[base + 2];
        float cdx = gx - px, cdy = gy - py;
        float dc = sqrtf(cdx * cdx + cdy * cdy + 1e-12f);
        float iou = (dc >= gr + pr) ? 0.0f : circle_iou(gx, gy, gr, px, py, pr);
        ov = iou * gmask;
        if (ov > 0.0f) {
            float sc = pd_scores[(size_t)(b * NA + a) * NC + gl] * gmask;
            float o2 = ov * ov;
            met = sc * (o2 * o2 * o2);          // score^1 * ov^6
        }
    }
    *ov_out = ov; *met_out = met;
}

// ---------------------------------------------------------------- mega kernel

__global__ __launch_bounds__(TPB, 4)
void k_mega(const float* __restrict__ pd_scores, const float* __restrict__ pd_circles,
            const float* __restrict__ anc, const int* __restrict__ gt_labels,
            const float* __restrict__ gt_circles, const float* __restrict__ mask_gt,
            int* __restrict__ plist_cnt, int* __restrict__ plist_a, float* __restrict__ plist_v,
            int* __restrict__ fg_count, int* __restrict__ sel_m,
            int* __restrict__ assigned, float* __restrict__ am_val,
            int* __restrict__ pos_align_i, int* __restrict__ pos_ov_i,
            float* __restrict__ out_labels, float* __restrict__ out_circ,
            float* __restrict__ out_scores, float* __restrict__ out_fg,
            float* __restrict__ out_gtidx) {
    cg::grid_group grid = cg::this_grid();
    const int tid  = threadIdx.x;
    const int bid  = blockIdx.x;
    const int gtid = bid * TPB + tid;
    const int GS   = NBLK * TPB;

    __shared__ float s_gx[B * M], s_gy[B * M], s_gr[B * M];
    __shared__ int   s_gl[B * M], s_act[B * M];    // s_gl = RAW label
    __shared__ int   s_sa[PCAP];
    __shared__ float s_sv[PCAP];
    __shared__ int   s_win[KK];

    // ---- P0: zero workspace; stage gt data into LDS (read-only inputs)
    for (int i = gtid; i < B * NA; i += GS) { fg_count[i] = 0; sel_m[i] = 0x7fffffff; }
    if (gtid < B * M) { pos_align_i[gtid] = 0; pos_ov_i[gtid] = 0; plist_cnt[gtid] = 0; }
    for (int i = tid; i < B * M; i += TPB) {
        s_act[i] = mask_gt[i] > 0.0f;
        s_gx[i] = gt_circles[i * 3 + 0];
        s_gy[i] = gt_circles[i * 3 + 1];
        s_gr[i] = gt_circles[i * 3 + 2];
        s_gl[i] = gt_labels[i];
    }
    __syncthreads();
    grid.sync();

    // ---- P1: per-anchor dense build of positive-metric lists
    for (int i = gtid; i < B * NA; i += GS) {
        int b = i / NA, a = i - b * NA;
        float2 ap = reinterpret_cast<const float2*>(anc)[a];
        float px = pd_circles[i * 3 + 0];   // coalesced stream
        float py = pd_circles[i * 3 + 1];
        float pr = pd_circles[i * 3 + 2];
        for (int m = 0; m < M; m++) {
            int gi = b * M + m;
            if (!s_act[gi]) continue;
            float gx = s_gx[gi], gy = s_gy[gi], gr = s_gr[gi];
            float dxa = ap.x - gx, dya = ap.y - gy;
            if (!(sqrtf(dxa * dxa + dya * dya) < gr)) continue;     // anchor in gt?
            float cdx = gx - px, cdy = gy - py;
            float dc = sqrtf(cdx * cdx + cdy * cdy + 1e-12f);
            if (dc >= gr + pr) continue;                            // circles disjoint -> iou 0
            float ov = circle_iou(gx, gy, gr, px, py, pr);          // gmask == 1 here
            if (!(ov > 0.0f)) continue;
            int gl = s_gl[gi]; gl = gl < 0 ? 0 : (gl > NC - 1 ? NC - 1 : gl);
            float sc = pd_scores[(size_t)i * NC + gl];
            float o2 = ov * ov;
            float met = sc * (o2 * o2 * o2);
            if (met > 0.0f) {
                int p = atomicAdd(&plist_cnt[gi], 1);
                if (p < PCAP) { plist_a[gi * PCAP + p] = a; plist_v[gi * PCAP + p] = met; }
            }
        }
    }
    grid.sync();

    // ---- P2: per-(b,m) top-13 select + scatter (blocks 0..511)
    bool selblk = (bid < B * M) && s_act[bid];
    int pcnt = 0;
    if (selblk) {
        pcnt = plist_cnt[bid]; if (pcnt > PCAP) pcnt = PCAP;
        for (int i = tid; i < pcnt; i += TPB) {
            s_sa[i] = plist_a[bid * PCAP + i];
            s_sv[i] = plist_v[bid * PCAP + i];
        }
    }
    __syncthreads();
    if (selblk && tid < 64) {
        int bm = bid, b = bm / M, m = bm - b * M;
        float gmask = mask_gt[bm];                 // == 1.0
        float gx = s_gx[bm], gy = s_gy[bm], gr = s_gr[bm];
        int gl = s_gl[bm]; gl = gl < 0 ? 0 : (gl > NC - 1 ? NC - 1 : gl);

        // 13 rounds of argmax (val desc, anchor asc) == lax.top_k order
        for (int k = 0; k < KK; k++) {
            float bv = 0.0f; int ba = 0x7fffffff; int bp = -1;
            for (int i = tid; i < pcnt; i += 64) {
                float v = s_sv[i];
                if (v > 0.0f) {
                    int a = s_sa[i];
                    if (v > bv || (v == bv && a < ba)) { bv = v; ba = a; bp = i; }
                }
            }
            for (int off = 32; off > 0; off >>= 1) {
                float v2 = __shfl_xor(bv, off);
                int   a2 = __shfl_xor(ba, off);
                int   p2 = __shfl_xor(bp, off);
                if (v2 > bv || (v2 == bv && a2 < ba)) { bv = v2; ba = a2; bp = p2; }
            }
            if (tid == 0) {
                if (bp >= 0) { s_win[k] = ba; s_sv[bp] = -1.0f; }
                else s_win[k] = -2;
            }
        }

        // zero-fill: top_k ties at 0 -> lowest anchor indices with metric == 0
        int defmask = 0;
        for (int k = 0; k < KK; k++) if (s_win[k] == -2) defmask |= (1 << k);
        if (defmask) {
            int astart = 0;
            while (defmask && astart < NA) {
                int a = astart + tid;
                bool zero = false;
                if (a < NA) {
                    float ov, met;
                    ov_met(pd_scores, pd_circles, anc, b, a, gx, gy, gr, gl, gmask, &ov, &met);
                    zero = !(met > 0.0f);
                }
                unsigned long long msk = __ballot(zero);
                while (msk && defmask) {
                    int bit = __ffsll((long long)msk) - 1; msk &= msk - 1;
                    int k2  = __ffs(defmask) - 1;          defmask &= defmask - 1;
                    if (tid == 0) s_win[k2] = astart + bit;
                }
                astart += 64;
            }
            while (defmask) {
                int k2 = __ffs(defmask) - 1; defmask &= defmask - 1;
                if (tid == 0) s_win[k2] = -1;
            }
        }

        // winners count only if anchor center inside the gt circle; scatter
        if (tid < KK) {
            int a = s_win[tid];
            if (a >= 0) {
                float ax = anc[2 * a], ay = anc[2 * a + 1];
                float dx = ax - gx, dy = ay - gy;
                if (sqrtf(dx * dx + dy * dy) < gr) {
                    atomicAdd(&fg_count[b * NA + a], 1);
                    atomicMin(&sel_m[b * NA + a], m);
                }
            }
        }
    }
    grid.sync();

    // ---- P3: per-anchor resolve + pos maxima (gt data from LDS)
    for (int i = gtid; i < B * NA; i += GS) {
        int b = i / NA, a = i - b * NA;
        int c = fg_count[i];
        int g = 0, fg = 0;
        if (c == 1) { g = sel_m[i]; fg = 1; }
        else if (c > 1) {
            // jnp.argmax over masked overlaps, lowest index wins ties
            float2 ap = reinterpret_cast<const float2*>(anc)[a];
            float px = pd_circles[i * 3 + 0];
            float py = pd_circles[i * 3 + 1];
            float pr = pd_circles[i * 3 + 2];
            float best = -1.0f; int bmx = 0;
            for (int mm = 0; mm < M; mm++) {
                int gi = b * M + mm;
                float ov = 0.0f;
                if (s_act[gi]) {
                    float gx = s_gx[gi], gy = s_gy[gi], grr = s_gr[gi];
                    float dx = ap.x - gx, dy = ap.y - gy;
                    if (sqrtf(dx * dx + dy * dy) < grr)
                        ov = circle_iou(gx, gy, grr, px, py, pr);
                }
                if (ov > best) { best = ov; bmx = mm; }
            }
            g = bmx; fg = 1;
        }
        assigned[i] = fg ? g : -1;
        int gi = b * M + g;
        int lbl = s_gl[gi]; if (lbl < 0) lbl = 0;      // clip(.., 0, None)
        out_labels[i] = (float)lbl;
        out_circ[(size_t)i * 3 + 0] = s_gx[gi];
        out_circ[(size_t)i * 3 + 1] = s_gy[gi];
        out_circ[(size_t)i * 3 + 2] = s_gr[gi];
        out_fg[i]    = fg ? 1.0f : 0.0f;
        out_gtidx[i] = (float)g;

        if (!fg) { am_val[i] = 0.0f; continue; }
        float gmask = mask_gt[gi];
        int gl2 = s_gl[gi]; gl2 = gl2 < 0 ? 0 : (gl2 > NC - 1 ? NC - 1 : gl2);
        float ov, met;
        ov_met(pd_scores, pd_circles, anc, b, a, s_gx[gi], s_gy[gi], s_gr[gi], gl2, gmask,
               &ov, &met);
        am_val[i] = met;
        atomicMax(&pos_align_i[gi], __float_as_int(met));   // values >= 0
        atomicMax(&pos_ov_i[gi],    __float_as_int(ov));
    }
    grid.sync();

    // ---- P4: target_scores (86 MB write)
    const int NQ = B * NA * NC / 4;
    for (int q = gtid; q < NQ; q += GS) {
        int row = q / (NC / 4);
        int c0  = (q - row * (NC / 4)) * 4;
        float4 v = make_float4(0.f, 0.f, 0.f, 0.f);
        int g = assigned[row];
        if (g >= 0) {
            int b = row / NA;
            float pa = __int_as_float(pos_align_i[b * M + g]);
            float po = __int_as_float(pos_ov_i[b * M + g]);
            float norm = am_val[row] * po / (pa + EPSF);
            int lbl = s_gl[b * M + g]; if (lbl < 0) lbl = 0;
            int off = lbl - c0;
            if (off >= 0 && off < 4) ((float*)&v)[off] = norm;
        }
        reinterpret_cast<float4*>(out_scores)[q] = v;
    }
}

// ---------------------------------------------------------------- launch

extern "C" void kernel_launch(void* const* d_in, const int* in_sizes, int n_in,
                              void* d_out, int out_size, void* d_ws, size_t ws_size,
                              hipStream_t stream) {
    const float* pd_scores  = (const float*)d_in[0];   // (B, NA, NC)
    const float* pd_circles = (const float*)d_in[1];   // (B, NA, 3)
    const float* anc        = (const float*)d_in[2];   // (NA, 2)
    const int*   gt_labels  = (const int*)  d_in[3];   // (B, M, 1)
    const float* gt_circles = (const float*)d_in[4];   // (B, M, 3)
    const float* mask_gt    = (const float*)d_in[5];   // (B, M, 1)

    // workspace layout
    char* w = (char*)d_ws;
    int*   plist_cnt   = (int*)w;   w += (size_t)B * M * sizeof(int);
    int*   plist_a     = (int*)w;   w += (size_t)B * M * PCAP * sizeof(int);
    float* plist_v     = (float*)w; w += (size_t)B * M * PCAP * sizeof(float);
    int*   fg_count    = (int*)w;   w += (size_t)B * NA * sizeof(int);
    int*   sel_m       = (int*)w;   w += (size_t)B * NA * sizeof(int);
    int*   assigned    = (int*)w;   w += (size_t)B * NA * sizeof(int);
    float* am_val      = (float*)w; w += (size_t)B * NA * sizeof(float);
    int*   pos_align_i = (int*)w;   w += (size_t)B * M * sizeof(int);
    int*   pos_ov_i    = (int*)w;   w += (size_t)B * M * sizeof(int);

    // output layout (concat in return order, float32)
    float* out        = (float*)d_out;
    float* out_labels = out;                              // B*NA
    float* out_circ   = out_labels + (size_t)B * NA;      // B*NA*3
    float* out_scores = out_circ + (size_t)B * NA * 3;    // B*NA*NC
    float* out_fg     = out_scores + (size_t)B * NA * NC; // B*NA
    float* out_gtidx  = out_fg + (size_t)B * NA;          // B*NA

    void* args[] = {
        (void*)&pd_scores, (void*)&pd_circles, (void*)&anc, (void*)&gt_labels,
        (void*)&gt_circles, (void*)&mask_gt,
        (void*)&plist_cnt, (void*)&plist_a, (void*)&plist_v,
        (void*)&fg_count, (void*)&sel_m, (void*)&assigned, (void*)&am_val,
        (void*)&pos_align_i, (void*)&pos_ov_i,
        (void*)&out_labels, (void*)&out_circ, (void*)&out_scores,
        (void*)&out_fg, (void*)&out_gtidx
    };
    hipLaunchCooperativeKernel((const void*)k_mega, dim3(NBLK), dim3(TPB),
                               args, 0, stream);
}

// Round 7
// 109.850 us; speedup vs baseline: 4.0988x; 4.0988x over previous
//
#include <hip/hip_runtime.h>
#include <math.h>

#define B   8
#define NA  33600
#define M   64
#define NC  80
#define KK  13
#define EPSF 1e-9f
#define PIF 3.14159265358979323846f

#define NPOS 1536          // per-(b,m) in-circle capacity (max ~1100 at gt_r=128)
#define TPB  256

// ---------------------------------------------------------------- helpers

__device__ __forceinline__ float circle_iou(float gx, float gy, float gr,
                                            float px, float py, float pr) {
    float dx = gx - px, dy = gy - py;
    float d  = sqrtf(dx * dx + dy * dy + 1e-12f);
    float r0sq = gr * gr, r1sq = pr * pr;
    float d1 = (r0sq - r1sq + d * d) / (2.0f * d);
    float d2 = d - d1;
    float t0 = fminf(fmaxf(d1 / fmaxf(gr, EPSF), -1.0f), 1.0f);
    float t1 = fminf(fmaxf(d2 / fmaxf(pr, EPSF), -1.0f), 1.0f);
    float a0 = r0sq * acosf(t0) - d1 * sqrtf(fmaxf(r0sq - d1 * d1, 0.0f));
    float a1 = r1sq * acosf(t1) - d2 * sqrtf(fmaxf(r1sq - d2 * d2, 0.0f));
    float lens = a0 + a1;
    float rmin = fminf(gr, pr);
    float contained = PIF * rmin * rmin;
    float inter = (d >= gr + pr) ? 0.0f
                : ((d <= fabsf(gr - pr)) ? contained : lens);
    float uni = PIF * r0sq + PIF * r1sq - inter;
    return (uni > 0.0f) ? inter / uni : 0.0f;
}

// masked overlap + align_metric for one (b, gt, anchor) — reference formula
__device__ __forceinline__ void ov_met(const float* __restrict__ pd_scores,
                                       const float* __restrict__ pd_circles,
                                       const float* __restrict__ anc,
                                       int b, int a,
                                       float gx, float gy, float gr, int gl, float gmask,
                                       float* ov_out, float* met_out) {
    float ax = anc[2 * a], ay = anc[2 * a + 1];
    float dx = ax - gx, dy = ay - gy;
    float dan = sqrtf(dx * dx + dy * dy);
    float ov = 0.0f, met = 0.0f;
    if (gmask > 0.0f && dan < gr) {
        int base = (b * NA + a) * 3;
        float px = pd_circles[base + 0];
        float py = pd_circles[base + 1];
        float pr = pd_circles[base + 2];
        float cdx = gx - px, cdy = gy - py;
        float dc = sqrtf(cdx * cdx + cdy * cdy + 1e-12f);
        float iou = (dc >= gr + pr) ? 0.0f : circle_iou(gx, gy, gr, px, py, pr);
        ov = iou * gmask;
        if (ov > 0.0f) {
            float sc = pd_scores[(size_t)(b * NA + a) * NC + gl] * gmask;
            float o2 = ov * ov;
            met = sc * (o2 * o2 * o2);          // score^1 * ov^6
        }
    }
    *ov_out = ov; *met_out = met;
}

// ---------------------------------------------------------------- K0 zero

__global__ void k_zero(int* __restrict__ fg_count, int* __restrict__ sel_m,
                       int* __restrict__ pos_align_i, int* __restrict__ pos_ov_i) {
    int i = blockIdx.x * blockDim.x + threadIdx.x;
    if (i < B * NA) { fg_count[i] = 0; sel_m[i] = 0x7fffffff; }
    if (i < B * M)  { pos_align_i[i] = 0; pos_ov_i[i] = 0; }
}

// ---------------------------------------------------------------- K1: fused per-(b,m) compact + metric + top-13 + scatter
// phase A: anc-only distance scan (L2-resident).
// phase B: gather pd_circles for ~375 in-circle; disjoint-cut before score gather (~7 survive).
// phase C: wave-0 selection, zero barriers; scatter <=13 atomics.

__global__ __launch_bounds__(TPB)
void k_bm(const float* __restrict__ pd_scores, const float* __restrict__ pd_circles,
          const float* __restrict__ anc, const int* __restrict__ gt_labels,
          const float* __restrict__ gt_circles, const float* __restrict__ mask_gt,
          int* __restrict__ fg_count, int* __restrict__ sel_m) {
    int bm = blockIdx.x;
    int b  = bm / M;
    int m  = bm - b * M;
    int tid = threadIdx.x;

    __shared__ int   s_cnt, s_pcnt;
    __shared__ int   s_a[NPOS];     // in-circle anchors
    __shared__ int   s_pa[NPOS];    // positive-metric anchors
    __shared__ float s_pv[NPOS];    // their metrics
    __shared__ int   s_win[KK];

    float gmask = mask_gt[bm];
    if (!(gmask > 0.0f)) return;               // inactive gt contributes nothing

    float gx = gt_circles[bm * 3 + 0];
    float gy = gt_circles[bm * 3 + 1];
    float gr = gt_circles[bm * 3 + 2];
    int gl = gt_labels[bm];
    gl = gl < 0 ? 0 : (gl > NC - 1 ? NC - 1 : gl);

    if (tid == 0) { s_cnt = 0; s_pcnt = 0; }
    __syncthreads();

    // phase A: anc-only distance scan, 2 anchors per iter (float4)
    for (int q = tid; q < NA / 2; q += TPB) {
        float4 p = reinterpret_cast<const float4*>(anc)[q];
        float dx0 = p.x - gx, dy0 = p.y - gy;
        float dx1 = p.z - gx, dy1 = p.w - gy;
        bool h0 = sqrtf(dx0 * dx0 + dy0 * dy0) < gr;
        bool h1 = sqrtf(dx1 * dx1 + dy1 * dy1) < gr;
        if (h0) { int p0 = atomicAdd(&s_cnt, 1); if (p0 < NPOS) s_a[p0] = 2 * q; }
        if (h1) { int p1 = atomicAdd(&s_cnt, 1); if (p1 < NPOS) s_a[p1] = 2 * q + 1; }
    }
    __syncthreads();
    int cnt = s_cnt; if (cnt > NPOS) cnt = NPOS;

    // phase B: gather pd_circles; disjoint cut; iou; score gather only for survivors
    for (int i = tid; i < cnt; i += TPB) {
        int a = s_a[i];
        int base = (b * NA + a) * 3;
        float px = pd_circles[base + 0];
        float py = pd_circles[base + 1];
        float pr = pd_circles[base + 2];
        float cdx = gx - px, cdy = gy - py;
        float dc = sqrtf(cdx * cdx + cdy * cdy + 1e-12f);
        if (dc >= gr + pr) continue;           // circles disjoint -> iou 0 -> met 0
        float ov = circle_iou(gx, gy, gr, px, py, pr);    // gmask == 1 here
        if (!(ov > 0.0f)) continue;
        float sc = pd_scores[(size_t)(b * NA + a) * NC + gl];
        float o2 = ov * ov;
        float met = sc * (o2 * o2 * o2);
        if (met > 0.0f) {
            int pp = atomicAdd(&s_pcnt, 1);    // pp < cnt <= NPOS guaranteed
            s_pa[pp] = a; s_pv[pp] = met;
        }
    }
    __syncthreads();

    if (tid >= 64) return;                     // selection: wave 0 only, no barriers below
    int pcnt = s_pcnt;

    // 13 rounds of argmax (val desc, anchor asc) == lax.top_k order
    for (int k = 0; k < KK; k++) {
        float bv = 0.0f; int ba = 0x7fffffff; int bp = -1;
        for (int i = tid; i < pcnt; i += 64) {
            float v = s_pv[i];
            if (v > 0.0f) {
                int a = s_pa[i];
                if (v > bv || (v == bv && a < ba)) { bv = v; ba = a; bp = i; }
            }
        }
        for (int off = 32; off > 0; off >>= 1) {
            float v2 = __shfl_xor(bv, off);
            int   a2 = __shfl_xor(ba, off);
            int   p2 = __shfl_xor(bp, off);
            if (v2 > bv || (v2 == bv && a2 < ba)) { bv = v2; ba = a2; bp = p2; }
        }
        if (tid == 0) {
            if (bp >= 0) { s_win[k] = ba; s_pv[bp] = -1.0f; }
            else s_win[k] = -2;
        }
    }

    // zero-fill: top_k ties at 0 -> lowest anchor indices with metric == 0
    int defmask = 0;
    for (int k = 0; k < KK; k++) if (s_win[k] == -2) defmask |= (1 << k);
    if (defmask) {
        int astart = 0;
        while (defmask && astart < NA) {
            int a = astart + tid;
            bool zero = false;
            if (a < NA) {
                float ov, met;
                ov_met(pd_scores, pd_circles, anc, b, a, gx, gy, gr, gl, gmask, &ov, &met);
                zero = !(met > 0.0f);
            }
            unsigned long long msk = __ballot(zero);
            while (msk && defmask) {
                int bit = __ffsll((long long)msk) - 1; msk &= msk - 1;
                int k2  = __ffs(defmask) - 1;          defmask &= defmask - 1;
                if (tid == 0) s_win[k2] = astart + bit;
            }
            astart += 64;
        }
        while (defmask) {
            int k2 = __ffs(defmask) - 1; defmask &= defmask - 1;
            if (tid == 0) s_win[k2] = -1;
        }
    }

    // winners enter mask_pos only if anchor center inside the gt circle; scatter
    if (tid < KK) {
        int a = s_win[tid];
        if (a >= 0) {
            float ax = anc[2 * a], ay = anc[2 * a + 1];
            float dx = ax - gx, dy = ay - gy;
            if (sqrtf(dx * dx + dy * dy) < gr) {
                atomicAdd(&fg_count[b * NA + a], 1);
                atomicMin(&sel_m[b * NA + a], m);
            }
        }
    }
}

// ---------------------------------------------------------------- K2 fused: per-anchor resolve + pos maxima

__global__ void k_resolve_posmax(const float* __restrict__ pd_scores,
                                 const float* __restrict__ pd_circles, const float* __restrict__ anc,
                                 const int* __restrict__ gt_labels, const float* __restrict__ gt_circles,
                                 const float* __restrict__ mask_gt,
                                 const int* __restrict__ fg_count, const int* __restrict__ sel_m,
                                 int* __restrict__ assigned, float* __restrict__ am_val,
                                 int* __restrict__ pos_align_i, int* __restrict__ pos_ov_i,
                                 float* __restrict__ out_labels, float* __restrict__ out_circles,
                                 float* __restrict__ out_fg, float* __restrict__ out_gtidx) {
    int i = blockIdx.x * blockDim.x + threadIdx.x;
    if (i >= B * NA) return;
    int b = i / NA, a = i - b * NA;
    int c = fg_count[i];
    int g = 0, fg = 0;
    if (c == 1) { g = sel_m[i]; fg = 1; }
    else if (c > 1) {
        // jnp.argmax over masked overlaps, lowest index wins ties
        float ax = anc[2 * a], ay = anc[2 * a + 1];
        int pbase = i * 3;
        float px = pd_circles[pbase], py = pd_circles[pbase + 1], pr = pd_circles[pbase + 2];
        float best = -1.0f; int bmx = 0;
        for (int mm = 0; mm < M; mm++) {
            float gmask = mask_gt[b * M + mm];
            float gx = gt_circles[(b * M + mm) * 3 + 0];
            float gy = gt_circles[(b * M + mm) * 3 + 1];
            float grr = gt_circles[(b * M + mm) * 3 + 2];
            float dx = ax - gx, dy = ay - gy;
            float ov = 0.0f;
            if (gmask > 0.0f && sqrtf(dx * dx + dy * dy) < grr)
                ov = circle_iou(gx, gy, grr, px, py, pr) * gmask;
            if (ov > best) { best = ov; bmx = mm; }
        }
        g = bmx; fg = 1;
    }
    assigned[i] = fg ? g : -1;
    int lbl = gt_labels[b * M + g]; if (lbl < 0) lbl = 0;   // clip(.., 0, None)
    out_labels[i] = (float)lbl;
    out_circles[(size_t)i * 3 + 0] = gt_circles[(b * M + g) * 3 + 0];
    out_circles[(size_t)i * 3 + 1] = gt_circles[(b * M + g) * 3 + 1];
    out_circles[(size_t)i * 3 + 2] = gt_circles[(b * M + g) * 3 + 2];
    out_fg[i]    = fg ? 1.0f : 0.0f;
    out_gtidx[i] = (float)g;

    if (!fg) { am_val[i] = 0.0f; return; }
    float gmask = mask_gt[b * M + g];
    float gx = gt_circles[(b * M + g) * 3 + 0];
    float gy = gt_circles[(b * M + g) * 3 + 1];
    float grc = gt_circles[(b * M + g) * 3 + 2];
    int gl2 = gt_labels[b * M + g];
    gl2 = gl2 < 0 ? 0 : (gl2 > NC - 1 ? NC - 1 : gl2);
    float ov, met;
    ov_met(pd_scores, pd_circles, anc, b, a, gx, gy, grc, gl2, gmask, &ov, &met);
    am_val[i] = met;
    atomicMax(&pos_align_i[b * M + g], __float_as_int(met));  // values >= 0
    atomicMax(&pos_ov_i[b * M + g],    __float_as_int(ov));
}

// ---------------------------------------------------------------- K3 target_scores (86 MB write)

__global__ void k_scores(const int* __restrict__ assigned, const float* __restrict__ am_val,
                         const int* __restrict__ pos_align_i, const int* __restrict__ pos_ov_i,
                         const int* __restrict__ gt_labels,
                         float* __restrict__ out_scores) {
    int q = blockIdx.x * blockDim.x + threadIdx.x;      // one float4 per thread
    if (q >= (B * NA * NC) / 4) return;
    int idx = q * 4;
    int row = idx / NC;
    int c0  = idx - row * NC;
    float4 v = make_float4(0.f, 0.f, 0.f, 0.f);
    int g = assigned[row];
    if (g >= 0) {
        int b = row / NA;
        float pa = __int_as_float(pos_align_i[b * M + g]);
        float po = __int_as_float(pos_ov_i[b * M + g]);
        float norm = am_val[row] * po / (pa + EPSF);
        int lbl = gt_labels[b * M + g]; if (lbl < 0) lbl = 0;
        int off = lbl - c0;
        if (off >= 0 && off < 4) ((float*)&v)[off] = norm;
    }
    reinterpret_cast<float4*>(out_scores)[q] = v;
}

// ---------------------------------------------------------------- launch

extern "C" void kernel_launch(void* const* d_in, const int* in_sizes, int n_in,
                              void* d_out, int out_size, void* d_ws, size_t ws_size,
                              hipStream_t stream) {
    const float* pd_scores  = (const float*)d_in[0];   // (B, NA, NC)
    const float* pd_circles = (const float*)d_in[1];   // (B, NA, 3)
    const float* anc        = (const float*)d_in[2];   // (NA, 2)
    const int*   gt_labels  = (const int*)  d_in[3];   // (B, M, 1)
    const float* gt_circles = (const float*)d_in[4];   // (B, M, 3)
    const float* mask_gt    = (const float*)d_in[5];   // (B, M, 1)

    // workspace layout
    char* w = (char*)d_ws;
    int*   fg_count    = (int*)w;   w += (size_t)B * NA * sizeof(int);
    int*   sel_m       = (int*)w;   w += (size_t)B * NA * sizeof(int);
    int*   assigned    = (int*)w;   w += (size_t)B * NA * sizeof(int);
    float* am_val      = (float*)w; w += (size_t)B * NA * sizeof(float);
    int*   pos_align_i = (int*)w;   w += (size_t)B * M * sizeof(int);
    int*   pos_ov_i    = (int*)w;   w += (size_t)B * M * sizeof(int);

    // output layout (concat in return order, float32)
    float* out        = (float*)d_out;
    float* out_labels = out;                              // B*NA
    float* out_circ   = out_labels + (size_t)B * NA;      // B*NA*3
    float* out_scores = out_circ + (size_t)B * NA * 3;    // B*NA*NC
    float* out_fg     = out_scores + (size_t)B * NA * NC; // B*NA
    float* out_gtidx  = out_fg + (size_t)B * NA;          // B*NA

    const int T = 256;
    int gBA = (B * NA + T - 1) / T;

    k_zero<<<gBA, T, 0, stream>>>(fg_count, sel_m, pos_align_i, pos_ov_i);

    k_bm<<<B * M, TPB, 0, stream>>>(pd_scores, pd_circles, anc, gt_labels,
                                    gt_circles, mask_gt, fg_count, sel_m);

    k_resolve_posmax<<<gBA, T, 0, stream>>>(pd_scores, pd_circles, anc, gt_labels,
                                            gt_circles, mask_gt, fg_count, sel_m,
                                            assigned, am_val, pos_align_i, pos_ov_i,
                                            out_labels, out_circ, out_fg, out_gtidx);

    int nq = (B * NA * NC) / 4;
    k_scores<<<(nq + T - 1) / T, T, 0, stream>>>(assigned, am_val, pos_align_i, pos_ov_i,
                                                 gt_labels, out_scores);
}